// Round 3
// baseline (178.612 us; speedup 1.0000x reference)
//
#include <hip/hip_runtime.h>

#define M_DIM 32
#define K_DIM 4096
#define N_DIM 12288
#define SPLITK 16
#define KPER (K_DIM / SPLITK)   // 256

// Kernel 1: zero the output accumulator (harness poisons d_out with 0xAA
// before timing and does not re-poison between replays).
__global__ __launch_bounds__(256) void qmm_zero(float* __restrict__ out) {
    int i = blockIdx.x * 256 + threadIdx.x;            // float4 index
    ((float4*)out)[i] = make_float4(0.f, 0.f, 0.f, 0.f);
}

// Kernel 2: raw-u8 dot products, split-K, atomicAdd into out.
// out[m,n] += sum_{k in slice} x[m,k] * (float)w[k,n]
// x reads are wave-uniform -> scalar loads (SMEM pipe);
// w reads are 256 consecutive dwords per block per k (fully coalesced).
__global__ __launch_bounds__(256) void qmm_main(const float* __restrict__ x,
                                                const int* __restrict__ w,
                                                float* __restrict__ out) {
    const int n  = blockIdx.x * 256 + threadIdx.x;
    const int k0 = blockIdx.y * KPER;

    float acc[M_DIM];
    #pragma unroll
    for (int m = 0; m < M_DIM; ++m) acc[m] = 0.f;

    const int* wp = w + (size_t)k0 * N_DIM + n;

    #pragma unroll 2
    for (int kk4 = 0; kk4 < KPER / 4; ++kk4) {
        const int kk = kk4 * 4;
        const float w0 = (float)wp[(size_t)(kk + 0) * N_DIM];
        const float w1 = (float)wp[(size_t)(kk + 1) * N_DIM];
        const float w2 = (float)wp[(size_t)(kk + 2) * N_DIM];
        const float w3 = (float)wp[(size_t)(kk + 3) * N_DIM];
        #pragma unroll
        for (int m = 0; m < M_DIM; ++m) {
            const float4 xv =
                *(const float4*)(x + (size_t)m * K_DIM + k0 + kk); // uniform
            acc[m] = fmaf(xv.x, w0, acc[m]);
            acc[m] = fmaf(xv.y, w1, acc[m]);
            acc[m] = fmaf(xv.z, w2, acc[m]);
            acc[m] = fmaf(xv.w, w3, acc[m]);
        }
    }

    #pragma unroll
    for (int m = 0; m < M_DIM; ++m)
        atomicAdd(&out[(size_t)m * N_DIM + n], acc[m]);
}

// Kernel 3: in-place affine correction.
// out[m,n] = scale[n] * (out[m,n] - zero[n] * rowsum[m])
// rowsum recomputed per block (16 KiB read, L2-resident).
__global__ __launch_bounds__(256) void qmm_scale(const float* __restrict__ x,
                                                 const float* __restrict__ scale,
                                                 const float* __restrict__ zero,
                                                 float* __restrict__ out) {
    const int m = blockIdx.y;
    __shared__ float red[256];
    float s = 0.f;
    for (int k = threadIdx.x; k < K_DIM; k += 256)
        s += x[(size_t)m * K_DIM + k];
    red[threadIdx.x] = s;
    __syncthreads();
    #pragma unroll
    for (int off = 128; off > 0; off >>= 1) {
        if (threadIdx.x < off) red[threadIdx.x] += red[threadIdx.x + off];
        __syncthreads();
    }
    const float rowsum = red[0];

    const int n = blockIdx.x * 256 + threadIdx.x;
    const float v = out[(size_t)m * N_DIM + n];
    out[(size_t)m * N_DIM + n] = scale[n] * (v - zero[n] * rowsum);
}

extern "C" void kernel_launch(void* const* d_in, const int* in_sizes, int n_in,
                              void* d_out, int out_size, void* d_ws, size_t ws_size,
                              hipStream_t stream) {
    const float* x     = (const float*)d_in[0];
    const int*   w     = (const int*)d_in[1];
    const float* scale = (const float*)d_in[2];   // fp16 in reference, but the
    const float* zero  = (const float*)d_in[3];   // harness delivers float32
    float* out = (float*)d_out;

    qmm_zero <<<dim3((M_DIM * N_DIM / 4) / 256), dim3(256), 0, stream>>>(out);
    qmm_main <<<dim3(N_DIM / 256, SPLITK),       dim3(256), 0, stream>>>(x, w, out);
    qmm_scale<<<dim3(N_DIM / 256, M_DIM),        dim3(256), 0, stream>>>(x, scale, zero, out);
}

// Round 4
// 135.873 us; speedup vs baseline: 1.3146x; 1.3146x over previous
//
#include <hip/hip_runtime.h>

#define M_DIM 32
#define K_DIM 4096
#define N_DIM 12288
#define SPLITK 32
#define KPER (K_DIM / SPLITK)   // 128
#define BLK 512                 // threads per block; block covers 512 n

// Kernel 1: zero the output accumulator (harness poisons d_out once and never
// re-poisons between replays; atomics below require zeroed start each call).
__global__ __launch_bounds__(256) void qmm_zero(float* __restrict__ out) {
    int i = blockIdx.x * 256 + threadIdx.x;            // float4 index
    ((float4*)out)[i] = make_float4(0.f, 0.f, 0.f, 0.f);
}

// Kernel 2: raw-u8 dot products, split-K, atomicAdd into out.
//   out[m,n] += sum_{k in slice} x[m,k] * (float)w[k,n]
// - weight loads: 1 dword/lane, 64 consecutive lanes -> fully coalesced;
//   unroll 8 -> 8 independent loads in flight per wave per phase.
// - x reads are wave-uniform -> scalar s_load (SMEM pipe), FMA consumes the
//   SGPR operand directly: zero VALU/LDS cost for x.
// - grid = 24 n-tiles x 32 K-slices = 768 blocks = 6144 waves (75% of slots).
__global__ __launch_bounds__(BLK, 6) void qmm_main(const float* __restrict__ x,
                                                   const int* __restrict__ w,
                                                   float* __restrict__ out) {
    const int n  = blockIdx.x * BLK + threadIdx.x;
    const int k0 = blockIdx.y * KPER;

    float acc[M_DIM];
    #pragma unroll
    for (int m = 0; m < M_DIM; ++m) acc[m] = 0.f;

    const int* wp = w + (size_t)k0 * N_DIM + n;

    for (int kg = 0; kg < KPER; kg += 8) {
        float wv[8];
        #pragma unroll
        for (int j = 0; j < 8; ++j)
            wv[j] = (float)wp[(size_t)(kg + j) * N_DIM];   // 8 loads in flight

        #pragma unroll
        for (int m = 0; m < M_DIM; ++m) {
            const float* xr = x + (size_t)m * K_DIM + k0 + kg;  // uniform, 32B
            #pragma unroll
            for (int j = 0; j < 8; ++j)
                acc[m] = fmaf(xr[j], wv[j], acc[m]);
        }
    }

    #pragma unroll
    for (int m = 0; m < M_DIM; ++m)
        atomicAdd(&out[(size_t)m * N_DIM + n], acc[m]);
}

// Kernel 3: in-place affine correction.
//   out[m,n] = scale[n] * (out[m,n] - zero[n] * rowsum[m])
__global__ __launch_bounds__(256) void qmm_scale(const float* __restrict__ x,
                                                 const float* __restrict__ scale,
                                                 const float* __restrict__ zero,
                                                 float* __restrict__ out) {
    const int m = blockIdx.y;
    __shared__ float red[256];
    float s = 0.f;
    for (int k = threadIdx.x; k < K_DIM; k += 256)
        s += x[(size_t)m * K_DIM + k];
    red[threadIdx.x] = s;
    __syncthreads();
    #pragma unroll
    for (int off = 128; off > 0; off >>= 1) {
        if (threadIdx.x < off) red[threadIdx.x] += red[threadIdx.x + off];
        __syncthreads();
    }
    const float rowsum = red[0];

    const int n = blockIdx.x * 256 + threadIdx.x;
    const float v = out[(size_t)m * N_DIM + n];
    out[(size_t)m * N_DIM + n] = scale[n] * (v - zero[n] * rowsum);
}

extern "C" void kernel_launch(void* const* d_in, const int* in_sizes, int n_in,
                              void* d_out, int out_size, void* d_ws, size_t ws_size,
                              hipStream_t stream) {
    const float* x     = (const float*)d_in[0];
    const int*   w     = (const int*)d_in[1];
    const float* scale = (const float*)d_in[2];   // fp16 in reference; harness
    const float* zero  = (const float*)d_in[3];   // delivers float32
    float* out = (float*)d_out;

    qmm_zero <<<dim3((M_DIM * N_DIM / 4) / 256), dim3(256), 0, stream>>>(out);
    qmm_main <<<dim3(N_DIM / BLK, SPLITK),       dim3(BLK), 0, stream>>>(x, w, out);
    qmm_scale<<<dim3(N_DIM / 256, M_DIM),        dim3(256), 0, stream>>>(x, scale, zero, out);
}

// Round 5
// 53.207 us; speedup vs baseline: 3.3569x; 2.5536x over previous
//
#include <hip/hip_runtime.h>

#define M_DIM 32
#define K_DIM 4096
#define N_DIM 12288
#define SPLITK 8
#define KPER  (K_DIM / SPLITK)     // 512 k per block
#define NT    (KPER / 32)          // 16 k-tiles of 32
#define BLK   512                  // 8 waves
#define NPB   128                  // n per block (8 waves x 16)

using bf16x8 = __attribute__((ext_vector_type(8))) short;
using f32x4  = __attribute__((ext_vector_type(4))) float;

// Kernel 1: zero the output accumulator (harness poisons once, never re-poisons).
__global__ __launch_bounds__(256) void qmm_zero(float* __restrict__ out) {
    int i = blockIdx.x * 256 + threadIdx.x;            // float4 index
    ((float4*)out)[i] = make_float4(0.f, 0.f, 0.f, 0.f);
}

__device__ __forceinline__ void load_b(const int* __restrict__ wp, int t, int (&wv)[8]) {
    #pragma unroll
    for (int j = 0; j < 8; ++j)
        wv[j] = wp[(size_t)(t * 32 + j) * N_DIM];      // 8 independent dword loads
}

__device__ __forceinline__ bf16x8 pack_b(const int (&wv)[8]) {
    bf16x8 b;
    #pragma unroll
    for (int j = 0; j < 8; ++j) {
        float f = (float)wv[j];                        // v_cvt_f32_i32, exact
        b[j] = (short)(__float_as_uint(f) >> 16);      // exact bf16: ints < 256 have 8 sig bits
    }
    return b;
}

// Kernel 2: MFMA bf16 GEMM on raw u8 weights, split-K, atomicAdd into out.
// Wave tile: 32m x 16n (two 16x16x32 MFMAs per 32-k tile).
// A (x) fragments built once per block into LDS; B (w) built in-register.
// A and B use the SAME (lane-group, elem)->k map, so the result is exact
// regardless of the HW's internal k interleave (A/B transpose symmetry).
__global__ __launch_bounds__(BLK, 6) void qmm_main(const float* __restrict__ x,
                                                   const int* __restrict__ w,
                                                   float* __restrict__ out) {
    __shared__ short lds_a[NT * 2 * 64 * 8];           // 32 KB: (ktile, m-half, lane) -> bf16x8

    const int tid  = threadIdx.x;
    const int lane = tid & 63;
    const int g    = lane >> 4;                        // k-group 0..3
    const int c    = lane & 15;                        // A row / B col within tile
    const int wid  = tid >> 6;
    const int k0   = blockIdx.y * KPER;
    const int n0   = blockIdx.x * NPB + wid * 16;

    // ---- one-time A-fragment build: bf16(x[16h + (l&15)][k0 + kt*32 + 8*(l>>4) + j]) ----
    for (int s = tid; s < NT * 2 * 64; s += BLK) {
        const int l  = s & 63;
        const int h  = (s >> 6) & 1;
        const int kt = s >> 7;
        const int m  = 16 * h + (l & 15);
        const float* xp = x + (size_t)m * K_DIM + k0 + kt * 32 + 8 * (l >> 4);
        bf16x8 v;
        #pragma unroll
        for (int j = 0; j < 8; ++j) {
            unsigned u = __float_as_uint(xp[j]);
            u += 0x7FFFu + ((u >> 16) & 1u);           // round-to-nearest-even to bf16
            v[j] = (short)(u >> 16);
        }
        *(bf16x8*)&lds_a[s * 8] = v;
    }
    __syncthreads();

    f32x4 acc0 = {0.f, 0.f, 0.f, 0.f};                 // m in [0,16)
    f32x4 acc1 = {0.f, 0.f, 0.f, 0.f};                 // m in [16,32)

    const int*   wp = w + (size_t)(k0 + 8 * g) * N_DIM + n0 + c;
    const short* la = lds_a + lane * 8;

    // ---- 2-deep software-pipelined k-tile loop ----
    int wvA[8], wvB[8];
    load_b(wp, 0, wvA);
    #pragma unroll
    for (int t = 0; t < NT; t += 2) {
        if (t + 1 < NT) load_b(wp, t + 1, wvB);
        {
            bf16x8 bf = pack_b(wvA);
            bf16x8 a0 = *(const bf16x8*)&la[(size_t)(t * 2 + 0) * 512];
            bf16x8 a1 = *(const bf16x8*)&la[(size_t)(t * 2 + 1) * 512];
            acc0 = __builtin_amdgcn_mfma_f32_16x16x32_bf16(a0, bf, acc0, 0, 0, 0);
            acc1 = __builtin_amdgcn_mfma_f32_16x16x32_bf16(a1, bf, acc1, 0, 0, 0);
        }
        if (t + 2 < NT) load_b(wp, t + 2, wvA);
        if (t + 1 < NT) {
            bf16x8 bf = pack_b(wvB);
            bf16x8 a0 = *(const bf16x8*)&la[(size_t)((t + 1) * 2 + 0) * 512];
            bf16x8 a1 = *(const bf16x8*)&la[(size_t)((t + 1) * 2 + 1) * 512];
            acc0 = __builtin_amdgcn_mfma_f32_16x16x32_bf16(a0, bf, acc0, 0, 0, 0);
            acc1 = __builtin_amdgcn_mfma_f32_16x16x32_bf16(a1, bf, acc1, 0, 0, 0);
        }
    }

    // ---- epilogue: verified C/D layout: row = 4*(lane>>4)+i, col = lane&15 ----
    #pragma unroll
    for (int i = 0; i < 4; ++i) {
        const int r = 4 * (lane >> 4) + i;
        atomicAdd(&out[(size_t)r * N_DIM + n0 + c], acc0[i]);
        atomicAdd(&out[(size_t)(16 + r) * N_DIM + n0 + c], acc1[i]);
    }
}

// Kernel 3: in-place affine correction.
//   out[m,n] = scale[n] * (out[m,n] - zero[n] * rowsum[m]); rowsum in fp32.
__global__ __launch_bounds__(256) void qmm_scale(const float* __restrict__ x,
                                                 const float* __restrict__ scale,
                                                 const float* __restrict__ zero,
                                                 float* __restrict__ out) {
    const int m = blockIdx.y;
    __shared__ float red[256];
    float s = 0.f;
    for (int k = threadIdx.x; k < K_DIM; k += 256)
        s += x[(size_t)m * K_DIM + k];
    red[threadIdx.x] = s;
    __syncthreads();
    #pragma unroll
    for (int off = 128; off > 0; off >>= 1) {
        if (threadIdx.x < off) red[threadIdx.x] += red[threadIdx.x + off];
        __syncthreads();
    }
    const float rowsum = red[0];

    const int n = blockIdx.x * 256 + threadIdx.x;
    const float v = out[(size_t)m * N_DIM + n];
    out[(size_t)m * N_DIM + n] = scale[n] * (v - zero[n] * rowsum);
}

extern "C" void kernel_launch(void* const* d_in, const int* in_sizes, int n_in,
                              void* d_out, int out_size, void* d_ws, size_t ws_size,
                              hipStream_t stream) {
    const float* x     = (const float*)d_in[0];
    const int*   w     = (const int*)d_in[1];
    const float* scale = (const float*)d_in[2];   // fp16 in reference; harness delivers fp32
    const float* zero  = (const float*)d_in[3];
    float* out = (float*)d_out;

    qmm_zero <<<dim3((M_DIM * N_DIM / 4) / 256), dim3(256), 0, stream>>>(out);
    qmm_main <<<dim3(N_DIM / NPB, SPLITK),       dim3(BLK), 0, stream>>>(x, w, out);
    qmm_scale<<<dim3(N_DIM / 256, M_DIM),        dim3(256), 0, stream>>>(x, scale, zero, out);
}

// Round 6
// 48.594 us; speedup vs baseline: 3.6756x; 1.0949x over previous
//
#include <hip/hip_runtime.h>

#define M_DIM 32
#define K_DIM 4096
#define N_DIM 12288
#define SPLITK 16
#define KPER  (K_DIM / SPLITK)     // 256 k per block
#define NT    (KPER / 32)          // 8 k-tiles of 32
#define BLK   512                  // 8 waves
#define NPB   128                  // n per block (8 waves x 16)

using bf16x8 = __attribute__((ext_vector_type(8))) short;
using f32x4  = __attribute__((ext_vector_type(4))) float;

__device__ __forceinline__ void load_b(const int* __restrict__ wp, int t, int (&wv)[8]) {
    #pragma unroll
    for (int j = 0; j < 8; ++j)
        wv[j] = wp[(size_t)(t * 32 + j) * N_DIM];      // 8 independent dword loads
}

__device__ __forceinline__ bf16x8 pack_b(const int (&wv)[8]) {
    bf16x8 b;
    #pragma unroll
    for (int j = 0; j < 8; ++j) {
        float f = (float)wv[j];                        // v_cvt_f32_i32, exact
        b[j] = (short)(__float_as_uint(f) >> 16);      // exact bf16: ints < 256
    }
    return b;
}

// MFMA bf16 GEMM on raw u8 weights, split-K.
// WS=true : store partials to part[s][m][n] (no atomics).
// WS=false: atomicAdd into out (fallback if workspace too small).
template <bool WS>
__global__ __launch_bounds__(BLK, 4) void qmm_main(const float* __restrict__ x,
                                                   const int* __restrict__ w,
                                                   float* __restrict__ dst) {
    __shared__ short lds_a[NT * 2 * 64 * 8];           // 16 KB

    const int tid  = threadIdx.x;
    const int lane = tid & 63;
    const int g    = lane >> 4;                        // k-group 0..3
    const int c    = lane & 15;                        // tile row/col index
    const int wid  = tid >> 6;
    const int k0   = blockIdx.y * KPER;
    const int n0   = blockIdx.x * NPB + wid * 16;

    // one-time A-build: bf16(x[16h + (l&15)][k0 + kt*32 + 8*(l>>4) + j])
    for (int s = tid; s < NT * 2 * 64; s += BLK) {
        const int l  = s & 63;
        const int h  = (s >> 6) & 1;
        const int kt = s >> 7;
        const int m  = 16 * h + (l & 15);
        const float* xp = x + (size_t)m * K_DIM + k0 + kt * 32 + 8 * (l >> 4);
        bf16x8 v;
        #pragma unroll
        for (int j = 0; j < 8; ++j) {
            unsigned u = __float_as_uint(xp[j]);
            u += 0x7FFFu + ((u >> 16) & 1u);           // RNE to bf16
            v[j] = (short)(u >> 16);
        }
        *(bf16x8*)&lds_a[s * 8] = v;
    }

    const int*   wp = w + (size_t)(k0 + 8 * g) * N_DIM + n0 + c;
    const short* la = lds_a + lane * 8;

    // prefetch 3 k-tiles of B before the barrier (independent of LDS)
    int wv[3][8];
    load_b(wp, 0, wv[0]);
    load_b(wp, 1, wv[1]);
    load_b(wp, 2, wv[2]);
    __syncthreads();

    f32x4 acc0 = {0.f, 0.f, 0.f, 0.f};                 // m in [0,16)
    f32x4 acc1 = {0.f, 0.f, 0.f, 0.f};                 // m in [16,32)

    #pragma unroll                                     // full unroll: static wv index
    for (int t = 0; t < NT; ++t) {
        bf16x8 bf = pack_b(wv[t % 3]);
        if (t + 3 < NT) load_b(wp, t + 3, wv[t % 3]);  // refill 3 ahead
        bf16x8 a0 = *(const bf16x8*)&la[(size_t)(t * 2 + 0) * 512];
        bf16x8 a1 = *(const bf16x8*)&la[(size_t)(t * 2 + 1) * 512];
        acc0 = __builtin_amdgcn_mfma_f32_16x16x32_bf16(a0, bf, acc0, 0, 0, 0);
        acc1 = __builtin_amdgcn_mfma_f32_16x16x32_bf16(a1, bf, acc1, 0, 0, 0);
    }

    // C/D layout (HW-verified): row = 4*(lane>>4)+i, col = lane&15
    if (WS) {
        float* pp = dst + ((size_t)blockIdx.y * M_DIM) * N_DIM + n0 + c;
        #pragma unroll
        for (int i = 0; i < 4; ++i) {
            const int r = 4 * (lane >> 4) + i;
            pp[(size_t)r * N_DIM]        = acc0[i];
            pp[(size_t)(16 + r) * N_DIM] = acc1[i];
        }
    } else {
        #pragma unroll
        for (int i = 0; i < 4; ++i) {
            const int r = 4 * (lane >> 4) + i;
            atomicAdd(&dst[(size_t)r * N_DIM + n0 + c], acc0[i]);
            atomicAdd(&dst[(size_t)(16 + r) * N_DIM + n0 + c], acc1[i]);
        }
    }
}

// Fused finalize: split-K reduce + affine correction.
//   out[m,n] = scale[n] * (sum_s part[s][m][n] - zero[n] * rowsum[m])
__global__ __launch_bounds__(256) void qmm_finalize(const float* __restrict__ part,
                                                    const float* __restrict__ x,
                                                    const float* __restrict__ scale,
                                                    const float* __restrict__ zero,
                                                    float* __restrict__ out) {
    const int m = blockIdx.y;
    __shared__ float red[256];
    float s = 0.f;
    for (int k = threadIdx.x; k < K_DIM; k += 256)
        s += x[(size_t)m * K_DIM + k];
    red[threadIdx.x] = s;
    __syncthreads();
    #pragma unroll
    for (int off = 128; off > 0; off >>= 1) {
        if (threadIdx.x < off) red[threadIdx.x] += red[threadIdx.x + off];
        __syncthreads();
    }
    const float rowsum = red[0];

    const int n = blockIdx.x * 256 + threadIdx.x;
    float acc = 0.f;
    #pragma unroll
    for (int sp = 0; sp < SPLITK; ++sp)
        acc += part[((size_t)sp * M_DIM + m) * N_DIM + n];
    out[(size_t)m * N_DIM + n] = scale[n] * (acc - zero[n] * rowsum);
}

// Fallback-path helpers (atomic route, only if ws too small)
__global__ __launch_bounds__(256) void qmm_zero(float* __restrict__ out) {
    int i = blockIdx.x * 256 + threadIdx.x;
    ((float4*)out)[i] = make_float4(0.f, 0.f, 0.f, 0.f);
}
__global__ __launch_bounds__(256) void qmm_scale(const float* __restrict__ x,
                                                 const float* __restrict__ scale,
                                                 const float* __restrict__ zero,
                                                 float* __restrict__ out) {
    const int m = blockIdx.y;
    __shared__ float red[256];
    float s = 0.f;
    for (int k = threadIdx.x; k < K_DIM; k += 256)
        s += x[(size_t)m * K_DIM + k];
    red[threadIdx.x] = s;
    __syncthreads();
    #pragma unroll
    for (int off = 128; off > 0; off >>= 1) {
        if (threadIdx.x < off) red[threadIdx.x] += red[threadIdx.x + off];
        __syncthreads();
    }
    const float rowsum = red[0];
    const int n = blockIdx.x * 256 + threadIdx.x;
    const float v = out[(size_t)m * N_DIM + n];
    out[(size_t)m * N_DIM + n] = scale[n] * (v - zero[n] * rowsum);
}

extern "C" void kernel_launch(void* const* d_in, const int* in_sizes, int n_in,
                              void* d_out, int out_size, void* d_ws, size_t ws_size,
                              hipStream_t stream) {
    const float* x     = (const float*)d_in[0];
    const int*   w     = (const int*)d_in[1];
    const float* scale = (const float*)d_in[2];   // fp16 in reference; harness delivers fp32
    const float* zero  = (const float*)d_in[3];
    float* out = (float*)d_out;

    const size_t need = (size_t)SPLITK * M_DIM * N_DIM * sizeof(float);  // 25.2 MB
    if (ws_size >= need) {
        float* part = (float*)d_ws;
        qmm_main<true><<<dim3(N_DIM / NPB, SPLITK), dim3(BLK), 0, stream>>>(x, w, part);
        qmm_finalize<<<dim3(N_DIM / 256, M_DIM),    dim3(256), 0, stream>>>(part, x, scale, zero, out);
    } else {
        qmm_zero <<<dim3((M_DIM * N_DIM / 4) / 256),  dim3(256), 0, stream>>>(out);
        qmm_main<false><<<dim3(N_DIM / NPB, SPLITK),  dim3(BLK), 0, stream>>>(x, w, out);
        qmm_scale<<<dim3(N_DIM / 256, M_DIM),         dim3(256), 0, stream>>>(x, scale, zero, out);
    }
}

// Round 7
// 45.989 us; speedup vs baseline: 3.8838x; 1.0567x over previous
//
#include <hip/hip_runtime.h>

#define M_DIM 32
#define K_DIM 4096
#define N_DIM 12288
#define SPLITK 16
#define KPER  (K_DIM / SPLITK)     // 256 k per block
#define NT    (KPER / 32)          // 8 k-tiles of 32
#define BLK   512                  // 8 waves
#define NPB   128                  // n per block

using bf16x8 = __attribute__((ext_vector_type(8))) short;
using f32x4  = __attribute__((ext_vector_type(4))) float;

typedef __attribute__((address_space(1))) const void GASV;
typedef __attribute__((address_space(3))) void LASV;

__device__ __forceinline__ bf16x8 pack_b(const int (&wv)[8]) {
    bf16x8 b;
    #pragma unroll
    for (int j = 0; j < 8; ++j) {
        float f = (float)wv[j];                        // v_cvt_f32_i32, exact
        b[j] = (short)(__float_as_uint(f) >> 16);      // exact bf16: ints < 256
    }
    return b;
}

// MFMA bf16 GEMM on raw u8 weights, split-K.
// B staged via global_load_lds dwordx4 (1 KiB contiguous per instr), double-
// buffered. LDS linear (DMA requires it); global source pre-swizzled (flip
// n-bit4 when local-row bit3 odd) so ds_read_b32 fragments are 2-way (free).
template <bool WS>
__global__ __launch_bounds__(BLK, 4) void qmm_main(const float* __restrict__ x,
                                                   const int* __restrict__ w,
                                                   float* __restrict__ dst) {
    __shared__ short lds_a[NT * 2 * 64 * 8];           // 16 KB bf16 A-frags
    __shared__ int   lds_b[2][32 * 128];               // 2 x 16 KB int32 B tiles

    const int tid  = threadIdx.x;
    const int lane = tid & 63;
    const int g    = lane >> 4;                        // k-group 0..3
    const int c    = lane & 15;                        // tile col index
    const int wid  = tid >> 6;
    const int k0   = blockIdx.y * KPER;
    const int n0   = blockIdx.x * NPB;
    const int n0w  = n0 + wid * 16;

    // ---- DMA source addressing: instr i = wid*2+q covers LDS dwords 256i.. ;
    // lane l writes dwords 256i+4l..+3 -> local row r = 2i + (l>>5),
    // nslot = 4*(l&31); global col = n0 + (nslot ^ (((r>>3)&1)<<4)).
    const int* gsrc[2];
    #pragma unroll
    for (int q = 0; q < 2; ++q) {
        const int i     = wid * 2 + q;
        const int r     = 2 * i + (lane >> 5);
        const int nslot = 4 * (lane & 31);
        const int col   = nslot ^ (((r >> 3) & 1) << 4);
        gsrc[q] = w + (size_t)(k0 + r) * N_DIM + n0 + col;
    }

    // ---- prologue: issue DMA for tiles 0,1 (fly during A-build) ----
    #pragma unroll
    for (int q = 0; q < 2; ++q) {
        __builtin_amdgcn_global_load_lds((GASV*)gsrc[q],
                                         (LASV*)&lds_b[0][(wid * 2 + q) * 256], 16, 0, 0);
        __builtin_amdgcn_global_load_lds((GASV*)(gsrc[q] + (size_t)32 * N_DIM),
                                         (LASV*)&lds_b[1][(wid * 2 + q) * 256], 16, 0, 0);
    }

    // ---- A-build: bf16(x[16h + (l&15)][k0 + kt*32 + 8*(l>>4) + j]) ----
    for (int s = tid; s < NT * 2 * 64; s += BLK) {
        const int l  = s & 63;
        const int h  = (s >> 6) & 1;
        const int kt = s >> 7;
        const int m  = 16 * h + (l & 15);
        const float* xp = x + (size_t)m * K_DIM + k0 + kt * 32 + 8 * (l >> 4);
        bf16x8 v;
        #pragma unroll
        for (int j = 0; j < 8; ++j) {
            unsigned u = __float_as_uint(xp[j]);
            u += 0x7FFFu + ((u >> 16) & 1u);           // RNE to bf16
            v[j] = (short)(u >> 16);
        }
        *(bf16x8*)&lds_a[s * 8] = v;
    }
    __syncthreads();                                   // drains DMA 0,1 + A writes

    f32x4 acc0 = {0.f, 0.f, 0.f, 0.f};                 // m in [0,16)
    f32x4 acc1 = {0.f, 0.f, 0.f, 0.f};                 // m in [16,32)

    const short* la     = lds_a + lane * 8;
    const int    colrd  = (wid * 16 + c) ^ ((g & 1) << 4);  // un-swizzle on read

    #pragma unroll                                     // static buf parity + stage idx
    for (int t = 0; t < NT; ++t) {
        const int* bb = &lds_b[t & 1][g * 8 * 128 + colrd];
        int wv[8];
        #pragma unroll
        for (int j = 0; j < 8; ++j) wv[j] = bb[j * 128];   // 2-way banked, free
        bf16x8 bf = pack_b(wv);
        bf16x8 a0 = *(const bf16x8*)&la[(size_t)(t * 2 + 0) * 512];
        bf16x8 a1 = *(const bf16x8*)&la[(size_t)(t * 2 + 1) * 512];
        acc0 = __builtin_amdgcn_mfma_f32_16x16x32_bf16(a0, bf, acc0, 0, 0, 0);
        acc1 = __builtin_amdgcn_mfma_f32_16x16x32_bf16(a1, bf, acc1, 0, 0, 0);

        __syncthreads();                               // all waves done with buf t&1
        if (t + 2 < NT) {                              // refill it with tile t+2
            #pragma unroll
            for (int q = 0; q < 2; ++q)
                __builtin_amdgcn_global_load_lds(
                    (GASV*)(gsrc[q] + (size_t)32 * (t + 2) * N_DIM),
                    (LASV*)&lds_b[t & 1][(wid * 2 + q) * 256], 16, 0, 0);
        }
    }

    // ---- epilogue: C/D layout (HW-verified): row = 4*(lane>>4)+i, col = lane&15
    if (WS) {
        float* pp = dst + ((size_t)blockIdx.y * M_DIM) * N_DIM + n0w + c;
        #pragma unroll
        for (int i = 0; i < 4; ++i) {
            const int r = 4 * (lane >> 4) + i;
            pp[(size_t)r * N_DIM]        = acc0[i];
            pp[(size_t)(16 + r) * N_DIM] = acc1[i];
        }
    } else {
        #pragma unroll
        for (int i = 0; i < 4; ++i) {
            const int r = 4 * (lane >> 4) + i;
            atomicAdd(&dst[(size_t)r * N_DIM + n0w + c], acc0[i]);
            atomicAdd(&dst[(size_t)(16 + r) * N_DIM + n0w + c], acc1[i]);
        }
    }
}

// rowsum[m] = sum_k x[m,k]  (32 blocks, float4 loads)
__global__ __launch_bounds__(256) void qmm_rowsum(const float* __restrict__ x,
                                                  float* __restrict__ rowsum) {
    const int m = blockIdx.x;
    __shared__ float red[256];
    const float4* xp = (const float4*)(x + (size_t)m * K_DIM);
    float s = 0.f;
    #pragma unroll
    for (int i = 0; i < K_DIM / 4 / 256; ++i) {
        float4 v = xp[threadIdx.x + 256 * i];
        s += v.x + v.y + v.z + v.w;
    }
    red[threadIdx.x] = s;
    __syncthreads();
    #pragma unroll
    for (int off = 128; off > 0; off >>= 1) {
        if (threadIdx.x < off) red[threadIdx.x] += red[threadIdx.x + off];
        __syncthreads();
    }
    if (threadIdx.x == 0) rowsum[m] = red[0];
}

// out[m,n] = scale[n] * (sum_s part[s][m][n] - zero[n] * rowsum[m]), float4-wide
__global__ __launch_bounds__(256) void qmm_finalize(const float* __restrict__ part,
                                                    const float* __restrict__ rowsum,
                                                    const float* __restrict__ scale,
                                                    const float* __restrict__ zero,
                                                    float* __restrict__ out) {
    const int m  = blockIdx.y;
    const int n4 = blockIdx.x * 256 + threadIdx.x;     // float4 index
    const float rs = rowsum[m];
    float4 acc = make_float4(0.f, 0.f, 0.f, 0.f);
    #pragma unroll
    for (int sp = 0; sp < SPLITK; ++sp) {
        float4 p = ((const float4*)(part + ((size_t)sp * M_DIM + m) * N_DIM))[n4];
        acc.x += p.x; acc.y += p.y; acc.z += p.z; acc.w += p.w;
    }
    const float4 sc = ((const float4*)scale)[n4];
    const float4 zp = ((const float4*)zero)[n4];
    float4 o;
    o.x = sc.x * (acc.x - zp.x * rs);
    o.y = sc.y * (acc.y - zp.y * rs);
    o.z = sc.z * (acc.z - zp.z * rs);
    o.w = sc.w * (acc.w - zp.w * rs);
    ((float4*)(out + (size_t)m * N_DIM))[n4] = o;
}

// Fallback-path helpers (atomic route, only if ws too small)
__global__ __launch_bounds__(256) void qmm_zero(float* __restrict__ out) {
    int i = blockIdx.x * 256 + threadIdx.x;
    ((float4*)out)[i] = make_float4(0.f, 0.f, 0.f, 0.f);
}
__global__ __launch_bounds__(256) void qmm_scale(const float* __restrict__ x,
                                                 const float* __restrict__ scale,
                                                 const float* __restrict__ zero,
                                                 float* __restrict__ out) {
    const int m = blockIdx.y;
    __shared__ float red[256];
    float s = 0.f;
    for (int k = threadIdx.x; k < K_DIM; k += 256)
        s += x[(size_t)m * K_DIM + k];
    red[threadIdx.x] = s;
    __syncthreads();
    #pragma unroll
    for (int off = 128; off > 0; off >>= 1) {
        if (threadIdx.x < off) red[threadIdx.x] += red[threadIdx.x + off];
        __syncthreads();
    }
    const float rowsum = red[0];
    const int n = blockIdx.x * 256 + threadIdx.x;
    const float v = out[(size_t)m * N_DIM + n];
    out[(size_t)m * N_DIM + n] = scale[n] * (v - zero[n] * rowsum);
}

extern "C" void kernel_launch(void* const* d_in, const int* in_sizes, int n_in,
                              void* d_out, int out_size, void* d_ws, size_t ws_size,
                              hipStream_t stream) {
    const float* x     = (const float*)d_in[0];
    const int*   w     = (const int*)d_in[1];
    const float* scale = (const float*)d_in[2];   // fp16 in reference; harness delivers fp32
    const float* zero  = (const float*)d_in[3];
    float* out = (float*)d_out;

    const size_t part_sz = (size_t)SPLITK * M_DIM * N_DIM * sizeof(float);  // 25.2 MB
    const size_t need    = part_sz + M_DIM * sizeof(float);
    if (ws_size >= need) {
        float* part   = (float*)d_ws;
        float* rowsum = (float*)((char*)d_ws + part_sz);
        qmm_main<true><<<dim3(N_DIM / NPB, SPLITK), dim3(BLK), 0, stream>>>(x, w, part);
        qmm_rowsum    <<<dim3(M_DIM),               dim3(256), 0, stream>>>(x, rowsum);
        qmm_finalize  <<<dim3(N_DIM / 4 / 256, M_DIM), dim3(256), 0, stream>>>(part, rowsum, scale, zero, out);
    } else {
        qmm_zero <<<dim3((M_DIM * N_DIM / 4) / 256),  dim3(256), 0, stream>>>(out);
        qmm_main<false><<<dim3(N_DIM / NPB, SPLITK),  dim3(BLK), 0, stream>>>(x, w, out);
        qmm_scale<<<dim3(N_DIM / 256, M_DIM),         dim3(256), 0, stream>>>(x, scale, zero, out);
    }
}

// Round 8
// 45.726 us; speedup vs baseline: 3.9061x; 1.0057x over previous
//
#include <hip/hip_runtime.h>

#define M_DIM 32
#define K_DIM 4096
#define N_DIM 12288
#define SPLITK 16
#define KPER  (K_DIM / SPLITK)     // 256 k per block
#define NT    (KPER / 32)          // 8 k-tiles of 32
#define BLK   512                  // 8 waves
#define NPB   128                  // n per block
#define DBUF  4                    // per-wave B buffer ring depth

using bf16x8 = __attribute__((ext_vector_type(8))) short;
using f32x4  = __attribute__((ext_vector_type(4))) float;

typedef __attribute__((address_space(1))) const void GASV;
typedef __attribute__((address_space(3))) void LASV;

// exact: ints in [0,256) have <=8 significand bits -> bf16 truncation lossless,
// and their f32 mantissa bits [15:0] are zero. v_perm packs two highs per dword.
__device__ __forceinline__ bf16x8 pack_b(const int (&wv)[8]) {
    union { unsigned u[4]; bf16x8 v; } r;
    #pragma unroll
    for (int p = 0; p < 4; ++p) {
        unsigned a = __float_as_uint((float)wv[2 * p]);
        unsigned b = __float_as_uint((float)wv[2 * p + 1]);
        r.u[p] = __builtin_amdgcn_perm(b, a, 0x07060302);  // [b.hi16 | a.hi16]
    }
    return r.v;
}

// MFMA bf16 GEMM on raw u8 weights, split-K, BARRIER-FREE K-loop:
// each wave DMAs its own 16 columns (2x global_load_lds of 1KiB) into its own
// LDS ring (4 bufs); safety = own-wave counted vmcnt only (never drained mid-loop).
// Source granule-XOR swizzle (LDS stays linear) spreads ds_read banks.
template <bool WS>
__global__ __launch_bounds__(BLK, 4) void qmm_main(const float* __restrict__ x,
                                                   const int* __restrict__ w,
                                                   float* __restrict__ dst) {
    __shared__ short lds_a[NT * 2 * 64 * 8];       // 16 KB bf16 A-frags
    __shared__ int   lds_b[8 * DBUF * 512];        // 64 KB: 8 waves x 4 bufs x 2KB

    const int tid  = threadIdx.x;
    const int lane = tid & 63;
    const int g    = lane >> 4;                    // k-group 0..3
    const int c    = lane & 15;                    // tile col
    const int wid  = tid >> 6;
    const int k0   = blockIdx.y * KPER;
    const int n0   = blockIdx.x * NPB;
    const int n0w  = n0 + wid * 16;

    // DMA source: instr q covers rows 16q..16q+15 of the 32xk tile; lane l ->
    // row r=16q+(l>>2), col granule (l&3) XOR ((r>>3)&3)  [inverse of read swizzle]
    const int* gsrc[2];
    #pragma unroll
    for (int q = 0; q < 2; ++q) {
        const int r  = 16 * q + (lane >> 2);
        const int cg = (lane & 3) ^ ((r >> 3) & 3);
        gsrc[q] = w + (size_t)(k0 + r) * N_DIM + n0w + 4 * cg;
    }
    int* const ldst = &lds_b[wid * (DBUF * 512)];

#define ISSUE(T) do {                                                          \
    __builtin_amdgcn_sched_barrier(0);                                         \
    __builtin_amdgcn_global_load_lds((GASV*)(gsrc[0] + (size_t)32 * (T) * N_DIM), \
        (LASV*)(ldst + ((T) & 3) * 512),       16, 0, 0);                      \
    __builtin_amdgcn_global_load_lds((GASV*)(gsrc[1] + (size_t)32 * (T) * N_DIM), \
        (LASV*)(ldst + ((T) & 3) * 512 + 256), 16, 0, 0);                      \
} while (0)

#define WAITV(N) do { asm volatile("s_waitcnt vmcnt(" #N ")" ::: "memory");    \
    __builtin_amdgcn_sched_barrier(0); } while (0)

    // prologue: 4 tiles in flight while A builds
    ISSUE(0); ISSUE(1); ISSUE(2); ISSUE(3);

    // A-build: bf16(x[16h + (l&15)][k0 + kt*32 + 8*(l>>4) + j])
    for (int s = tid; s < NT * 2 * 64; s += BLK) {
        const int l  = s & 63;
        const int h  = (s >> 6) & 1;
        const int kt = s >> 7;
        const int m  = 16 * h + (l & 15);
        const float* xp = x + (size_t)m * K_DIM + k0 + kt * 32 + 8 * (l >> 4);
        bf16x8 v;
        #pragma unroll
        for (int j = 0; j < 8; ++j) {
            unsigned u = __float_as_uint(xp[j]);
            u += 0x7FFFu + ((u >> 16) & 1u);       // RNE to bf16
            v[j] = (short)(u >> 16);
        }
        *(bf16x8*)&lds_a[s * 8] = v;
    }
    __syncthreads();                               // ONE barrier: A ready, B0..3 resident

    // A-frags to registers (static indices); lds_a dead afterwards
    bf16x8 areg[NT * 2];
    {
        const short* la = lds_a + lane * 8;
        #pragma unroll
        for (int i = 0; i < NT * 2; ++i)
            areg[i] = *(const bf16x8*)&la[(size_t)i * 512];
    }

    // B read base: slot(r=8g+j, col c) = r*16 + 4*((c>>2)^g) + (c&3); j -> imm offset
    const int* brd = lds_b + wid * (DBUF * 512) + 128 * g + 4 * ((c >> 2) ^ g) + (c & 3);

    f32x4 acc0 = {0.f, 0.f, 0.f, 0.f};             // m in [0,16)
    f32x4 acc1 = {0.f, 0.f, 0.f, 0.f};             // m in [16,32)

#define COMP(T) do {                                                           \
    int wv[8];                                                                 \
    _Pragma("unroll")                                                          \
    for (int j = 0; j < 8; ++j) wv[j] = brd[((T) & 3) * 512 + j * 16];         \
    bf16x8 bfv = pack_b(wv);                                                   \
    acc0 = __builtin_amdgcn_mfma_f32_16x16x32_bf16(areg[2*(T)],   bfv, acc0, 0, 0, 0); \
    acc1 = __builtin_amdgcn_mfma_f32_16x16x32_bf16(areg[2*(T)+1], bfv, acc1, 0, 0, 0); \
} while (0)

    // barrier-free pipelined K-loop; vmcnt counted, never drained until the tail
    COMP(0); ISSUE(4);
    COMP(1); ISSUE(5);
    COMP(2); ISSUE(6);
    COMP(3); ISSUE(7);
    WAITV(6); COMP(4);
    WAITV(4); COMP(5);
    WAITV(2); COMP(6);
    WAITV(0); COMP(7);

#undef ISSUE
#undef WAITV
#undef COMP

    // epilogue: C/D layout (HW-verified): row = 4*(lane>>4)+i, col = lane&15
    if (WS) {
        float* pp = dst + ((size_t)blockIdx.y * M_DIM) * N_DIM + n0w + c;
        #pragma unroll
        for (int i = 0; i < 4; ++i) {
            const int r = 4 * (lane >> 4) + i;
            pp[(size_t)r * N_DIM]        = acc0[i];
            pp[(size_t)(16 + r) * N_DIM] = acc1[i];
        }
    } else {
        #pragma unroll
        for (int i = 0; i < 4; ++i) {
            const int r = 4 * (lane >> 4) + i;
            atomicAdd(&dst[(size_t)r * N_DIM + n0w + c], acc0[i]);
            atomicAdd(&dst[(size_t)(16 + r) * N_DIM + n0w + c], acc1[i]);
        }
    }
}

// rowsum[m] = sum_k x[m,k]  (32 blocks, float4 loads)
__global__ __launch_bounds__(256) void qmm_rowsum(const float* __restrict__ x,
                                                  float* __restrict__ rowsum) {
    const int m = blockIdx.x;
    __shared__ float red[256];
    const float4* xp = (const float4*)(x + (size_t)m * K_DIM);
    float s = 0.f;
    #pragma unroll
    for (int i = 0; i < K_DIM / 4 / 256; ++i) {
        float4 v = xp[threadIdx.x + 256 * i];
        s += v.x + v.y + v.z + v.w;
    }
    red[threadIdx.x] = s;
    __syncthreads();
    #pragma unroll
    for (int off = 128; off > 0; off >>= 1) {
        if (threadIdx.x < off) red[threadIdx.x] += red[threadIdx.x + off];
        __syncthreads();
    }
    if (threadIdx.x == 0) rowsum[m] = red[0];
}

// out[m,n] = scale[n] * (sum_s part[s][m][n] - zero[n] * rowsum[m]), float4-wide
__global__ __launch_bounds__(256) void qmm_finalize(const float* __restrict__ part,
                                                    const float* __restrict__ rowsum,
                                                    const float* __restrict__ scale,
                                                    const float* __restrict__ zero,
                                                    float* __restrict__ out) {
    const int m  = blockIdx.y;
    const int n4 = blockIdx.x * 256 + threadIdx.x;
    const float rs = rowsum[m];
    float4 acc = make_float4(0.f, 0.f, 0.f, 0.f);
    #pragma unroll
    for (int sp = 0; sp < SPLITK; ++sp) {
        float4 p = ((const float4*)(part + ((size_t)sp * M_DIM + m) * N_DIM))[n4];
        acc.x += p.x; acc.y += p.y; acc.z += p.z; acc.w += p.w;
    }
    const float4 sc = ((const float4*)scale)[n4];
    const float4 zp = ((const float4*)zero)[n4];
    float4 o;
    o.x = sc.x * (acc.x - zp.x * rs);
    o.y = sc.y * (acc.y - zp.y * rs);
    o.z = sc.z * (acc.z - zp.z * rs);
    o.w = sc.w * (acc.w - zp.w * rs);
    ((float4*)(out + (size_t)m * N_DIM))[n4] = o;
}

// Fallback-path helpers (atomic route, only if ws too small)
__global__ __launch_bounds__(256) void qmm_zero(float* __restrict__ out) {
    int i = blockIdx.x * 256 + threadIdx.x;
    ((float4*)out)[i] = make_float4(0.f, 0.f, 0.f, 0.f);
}
__global__ __launch_bounds__(256) void qmm_scale(const float* __restrict__ x,
                                                 const float* __restrict__ scale,
                                                 const float* __restrict__ zero,
                                                 float* __restrict__ out) {
    const int m = blockIdx.y;
    __shared__ float red[256];
    float s = 0.f;
    for (int k = threadIdx.x; k < K_DIM; k += 256)
        s += x[(size_t)m * K_DIM + k];
    red[threadIdx.x] = s;
    __syncthreads();
    #pragma unroll
    for (int off = 128; off > 0; off >>= 1) {
        if (threadIdx.x < off) red[threadIdx.x] += red[threadIdx.x + off];
        __syncthreads();
    }
    const float rowsum = red[0];
    const int n = blockIdx.x * 256 + threadIdx.x;
    const float v = out[(size_t)m * N_DIM + n];
    out[(size_t)m * N_DIM + n] = scale[n] * (v - zero[n] * rowsum);
}

extern "C" void kernel_launch(void* const* d_in, const int* in_sizes, int n_in,
                              void* d_out, int out_size, void* d_ws, size_t ws_size,
                              hipStream_t stream) {
    const float* x     = (const float*)d_in[0];
    const int*   w     = (const int*)d_in[1];
    const float* scale = (const float*)d_in[2];   // fp16 in reference; harness delivers fp32
    const float* zero  = (const float*)d_in[3];
    float* out = (float*)d_out;

    const size_t part_sz = (size_t)SPLITK * M_DIM * N_DIM * sizeof(float);  // 25.2 MB
    const size_t need    = part_sz + M_DIM * sizeof(float);
    if (ws_size >= need) {
        float* part   = (float*)d_ws;
        float* rowsum = (float*)((char*)d_ws + part_sz);
        qmm_main<true><<<dim3(N_DIM / NPB, SPLITK), dim3(BLK), 0, stream>>>(x, w, part);
        qmm_rowsum    <<<dim3(M_DIM),               dim3(256), 0, stream>>>(x, rowsum);
        qmm_finalize  <<<dim3(N_DIM / 4 / 256, M_DIM), dim3(256), 0, stream>>>(part, rowsum, scale, zero, out);
    } else {
        qmm_zero <<<dim3((M_DIM * N_DIM / 4) / 256),  dim3(256), 0, stream>>>(out);
        qmm_main<false><<<dim3(N_DIM / NPB, SPLITK),  dim3(BLK), 0, stream>>>(x, w, out);
        qmm_scale<<<dim3(N_DIM / 256, M_DIM),         dim3(256), 0, stream>>>(x, scale, zero, out);
    }
}